// Round 1
// baseline (604.399 us; speedup 1.0000x reference)
//
#include <hip/hip_runtime.h>

#define N_NODES 10000
#define N_EDGES 160000
#define FEAT 512

// ---------------- degree count ----------------
__global__ void deg_kernel(const int* __restrict__ src, const int* __restrict__ dst,
                           int* __restrict__ deg_out, int* __restrict__ deg_in) {
    int e = blockIdx.x * blockDim.x + threadIdx.x;
    if (e < N_EDGES) {
        atomicAdd(&deg_out[src[e]], 1);
        atomicAdd(&deg_in[dst[e]], 1);
    }
}

// ---------------- norms = deg^{-1/2} (0 if deg==0) ----------------
__global__ void norm_kernel(const int* __restrict__ deg_out, const int* __restrict__ deg_in,
                            float* __restrict__ norm_out, float* __restrict__ norm_in) {
    int i = blockIdx.x * blockDim.x + threadIdx.x;
    if (i < N_NODES) {
        int dob = deg_out[i], dib = deg_in[i];
        norm_out[i] = dob > 0 ? rsqrtf((float)dob) : 0.f;
        norm_in[i]  = dib > 0 ? rsqrtf((float)dib) : 0.f;
    }
}

// ---------------- exclusive scan of in-degrees -> row_ptr, cursor ----------------
__global__ void scan_kernel(const int* __restrict__ deg_in,
                            int* __restrict__ row_ptr, int* __restrict__ cursor) {
    __shared__ int sums[256];
    const int CHUNK = 40;  // 256*40 = 10240 >= N_NODES
    int t = threadIdx.x;
    int start = t * CHUNK;
    int s = 0;
    for (int j = 0; j < CHUNK; j++) {
        int i = start + j;
        if (i < N_NODES) s += deg_in[i];
    }
    sums[t] = s;
    __syncthreads();
    for (int off = 1; off < 256; off <<= 1) {
        int v = (t >= off) ? sums[t - off] : 0;
        __syncthreads();
        sums[t] += v;
        __syncthreads();
    }
    int run = (t > 0) ? sums[t - 1] : 0;
    for (int j = 0; j < CHUNK; j++) {
        int i = start + j;
        if (i < N_NODES) {
            row_ptr[i] = run;
            cursor[i] = run;
            run += deg_in[i];
        }
    }
    if (t == 0) row_ptr[N_NODES] = sums[255];
}

// ---------------- CSR fill (bucket edges by dst) ----------------
__global__ void fill_kernel(const int* __restrict__ src, const int* __restrict__ dst,
                            int* __restrict__ cursor, int* __restrict__ edge_src) {
    int e = blockIdx.x * blockDim.x + threadIdx.x;
    if (e < N_EDGES) {
        int d = dst[e];
        int pos = atomicAdd(&cursor[d], 1);
        edge_src[pos] = src[e];
    }
}

// ---------------- aggregation: out[d] = norm_in[d] * sum_{s in N(d)} norm_out[s]*x[s] ----------------
__global__ __launch_bounds__(128) void agg_kernel(const float* __restrict__ x,
                                                  const int* __restrict__ edge_src,
                                                  const int* __restrict__ row_ptr,
                                                  const float* __restrict__ norm_out,
                                                  const float* __restrict__ norm_in,
                                                  float* __restrict__ out) {
    int d = blockIdx.x;
    int t = threadIdx.x;  // 128 threads x float4 = 512 feats
    int beg = row_ptr[d], end = row_ptr[d + 1];
    const float4* x4 = (const float4*)x;
    float4 acc = make_float4(0.f, 0.f, 0.f, 0.f);
    for (int e = beg; e < end; e++) {
        int s = edge_src[e];
        float w = norm_out[s];
        float4 v = x4[s * (FEAT / 4) + t];
        acc.x += w * v.x;
        acc.y += w * v.y;
        acc.z += w * v.z;
        acc.w += w * v.w;
    }
    float ni = norm_in[d];
    acc.x *= ni; acc.y *= ni; acc.z *= ni; acc.w *= ni;
    ((float4*)out)[d * (FEAT / 4) + t] = acc;
}

// ---------------- fp32 tiled GEMM: C = A(MxK) @ B(KxN) + bias (opt relu) ----------------
// K = N = 512 fixed. BM=BN=64, BK=16, 256 threads, 4x4 microtile.
template <bool RELU>
__global__ __launch_bounds__(256) void gemm_kernel(const float* __restrict__ A,
                                                   const float* __restrict__ B,
                                                   const float* __restrict__ bias,
                                                   float* __restrict__ C, int M) {
    const int BK = 16;
    __shared__ float As[BK][64 + 4];  // transposed tile, +4 pad keeps f4 align
    __shared__ float Bs[BK][64];
    int t = threadIdx.x;
    int row0 = blockIdx.x * 64;
    int col0 = blockIdx.y * 64;
    int tm = t >> 4, tn = t & 15;
    int aRow = t >> 2, aK = (t & 3) * 4;
    int bRow = t >> 4, bCol = (t & 15) * 4;
    float acc[4][4] = {};
    for (int k0 = 0; k0 < 512; k0 += BK) {
        float4 av;
        int ar = row0 + aRow;
        if (ar < M) av = *(const float4*)&A[ar * 512 + k0 + aK];
        else av = make_float4(0.f, 0.f, 0.f, 0.f);
        As[aK + 0][aRow] = av.x;
        As[aK + 1][aRow] = av.y;
        As[aK + 2][aRow] = av.z;
        As[aK + 3][aRow] = av.w;
        *(float4*)&Bs[bRow][bCol] = *(const float4*)&B[(k0 + bRow) * 512 + col0 + bCol];
        __syncthreads();
#pragma unroll
        for (int k = 0; k < BK; k++) {
            float4 a4 = *(const float4*)&As[k][tm * 4];
            float4 b4 = *(const float4*)&Bs[k][tn * 4];
            float avv[4] = {a4.x, a4.y, a4.z, a4.w};
            float bvv[4] = {b4.x, b4.y, b4.z, b4.w};
#pragma unroll
            for (int i = 0; i < 4; i++)
#pragma unroll
                for (int j = 0; j < 4; j++)
                    acc[i][j] += avv[i] * bvv[j];
        }
        __syncthreads();
    }
#pragma unroll
    for (int i = 0; i < 4; i++) {
        int r = row0 + tm * 4 + i;
        if (r < M) {
            float4 o;
            float* op = &o.x;
#pragma unroll
            for (int j = 0; j < 4; j++) {
                float v = acc[i][j] + bias[col0 + tn * 4 + j];
                if (RELU) v = fmaxf(v, 0.f);
                op[j] = v;
            }
            *(float4*)&C[r * 512 + col0 + tn * 4] = o;
        }
    }
}

extern "C" void kernel_launch(void* const* d_in, const int* in_sizes, int n_in,
                              void* d_out, int out_size, void* d_ws, size_t ws_size,
                              hipStream_t stream) {
    const float* x  = (const float*)d_in[0];
    const float* W1 = (const float*)d_in[1];
    const float* b1 = (const float*)d_in[2];
    const float* W2 = (const float*)d_in[3];
    const float* b2 = (const float*)d_in[4];
    const float* W3 = (const float*)d_in[5];
    const float* b3 = (const float*)d_in[6];
    const int* src  = (const int*)d_in[7];
    const int* dst  = (const int*)d_in[8];
    float* out = (float*)d_out;

    // workspace layout (ints)
    int* wsi = (int*)d_ws;
    int* deg_out  = wsi;           // 10000
    int* deg_in   = wsi + 10000;   // 10000
    float* norm_out = (float*)(wsi + 20000);  // 10000
    float* norm_in  = (float*)(wsi + 30000);  // 10000
    int* row_ptr  = wsi + 40000;   // 10001
    int* cursor   = wsi + 50004;   // 10000
    int* edge_src = wsi + 60004;   // 160000
    float* agg = (float*)(wsi + 220004);  // 5,120,000 floats, 16B-aligned

    // d_out layout: [h4 | h3 | h2], each 10000x512. Stage h1 in the h4 slot
    // (h4 is written last, h1 dead by then).
    float* h4 = out;
    float* h1 = out;                 // staged, overwritten by h4 at the end
    float* h3 = out + 5120000;
    float* h2 = out + 10240000;

    hipMemsetAsync(d_ws, 0, 20000 * sizeof(int), stream);  // deg_out + deg_in

    deg_kernel<<<(N_EDGES + 255) / 256, 256, 0, stream>>>(src, dst, deg_out, deg_in);
    norm_kernel<<<(N_NODES + 255) / 256, 256, 0, stream>>>(deg_out, deg_in, norm_out, norm_in);
    scan_kernel<<<1, 256, 0, stream>>>(deg_in, row_ptr, cursor);
    fill_kernel<<<(N_EDGES + 255) / 256, 256, 0, stream>>>(src, dst, cursor, edge_src);

    dim3 ggrid((N_NODES + 63) / 64, 8);

    // layer 1
    agg_kernel<<<N_NODES, 128, 0, stream>>>(x, edge_src, row_ptr, norm_out, norm_in, agg);
    gemm_kernel<true><<<ggrid, 256, 0, stream>>>(agg, W1, b1, h1, N_NODES);
    // layer 2
    agg_kernel<<<N_NODES, 128, 0, stream>>>(h1, edge_src, row_ptr, norm_out, norm_in, agg);
    gemm_kernel<true><<<ggrid, 256, 0, stream>>>(agg, W2, b2, h2, N_NODES);
    // layers 3 & 4 share the aggregation of h2
    agg_kernel<<<N_NODES, 128, 0, stream>>>(h2, edge_src, row_ptr, norm_out, norm_in, agg);
    gemm_kernel<true><<<ggrid, 256, 0, stream>>>(agg, W2, b2, h3, N_NODES);
    gemm_kernel<false><<<ggrid, 256, 0, stream>>>(agg, W3, b3, h4, N_NODES);
}

// Round 2
// 396.419 us; speedup vs baseline: 1.5246x; 1.5246x over previous
//
#include <hip/hip_runtime.h>

#define N_NODES 10000
#define N_EDGES 160000
#define FEAT 512
#define M_PAD 10048   // 157 * 64

typedef unsigned short ushort_t;
typedef unsigned int uint32;

typedef __attribute__((ext_vector_type(8))) short short8;   // 8 bf16 (4 VGPRs)
typedef __attribute__((ext_vector_type(4))) float f32x4;    // MFMA C/D

__device__ __forceinline__ ushort_t f2bf(float f) {
    uint32 u = __float_as_uint(f);
    u += 0x7FFF + ((u >> 16) & 1);   // round-to-nearest-even
    return (ushort_t)(u >> 16);
}
__device__ __forceinline__ float bf2f(ushort_t h) {
    return __uint_as_float(((uint32)h) << 16);
}

__device__ __forceinline__ void load_lds16(const ushort_t* g, ushort_t* l) {
    __builtin_amdgcn_global_load_lds(
        (const __attribute__((address_space(1))) void*)g,
        (__attribute__((address_space(3))) void*)l, 16, 0, 0);
}

// ---------------- degree count ----------------
__global__ void deg_kernel(const int* __restrict__ src, const int* __restrict__ dst,
                           int* __restrict__ deg_out, int* __restrict__ deg_in) {
    int e = blockIdx.x * blockDim.x + threadIdx.x;
    if (e < N_EDGES) {
        atomicAdd(&deg_out[src[e]], 1);
        atomicAdd(&deg_in[dst[e]], 1);
    }
}

// ---------------- norms ----------------
__global__ void norm_kernel(const int* __restrict__ deg_out, const int* __restrict__ deg_in,
                            float* __restrict__ norm_out, float* __restrict__ norm_in) {
    int i = blockIdx.x * blockDim.x + threadIdx.x;
    if (i < N_NODES) {
        int dob = deg_out[i], dib = deg_in[i];
        norm_out[i] = dob > 0 ? rsqrtf((float)dob) : 0.f;
        norm_in[i]  = dib > 0 ? rsqrtf((float)dib) : 0.f;
    }
}

// ---------------- exclusive scan of in-degrees ----------------
__global__ void scan_kernel(const int* __restrict__ deg_in,
                            int* __restrict__ row_ptr, int* __restrict__ cursor) {
    __shared__ int sums[256];
    const int CHUNK = 40;
    int t = threadIdx.x;
    int start = t * CHUNK;
    int s = 0;
    for (int j = 0; j < CHUNK; j++) {
        int i = start + j;
        if (i < N_NODES) s += deg_in[i];
    }
    sums[t] = s;
    __syncthreads();
    for (int off = 1; off < 256; off <<= 1) {
        int v = (t >= off) ? sums[t - off] : 0;
        __syncthreads();
        sums[t] += v;
        __syncthreads();
    }
    int run = (t > 0) ? sums[t - 1] : 0;
    for (int j = 0; j < CHUNK; j++) {
        int i = start + j;
        if (i < N_NODES) {
            row_ptr[i] = run;
            cursor[i] = run;
            run += deg_in[i];
        }
    }
    if (t == 0) row_ptr[N_NODES] = sums[255];
}

// ---------------- CSR fill ----------------
__global__ void fill_kernel(const int* __restrict__ src, const int* __restrict__ dst,
                            int* __restrict__ cursor, int* __restrict__ edge_src) {
    int e = blockIdx.x * blockDim.x + threadIdx.x;
    if (e < N_EDGES) {
        int d = dst[e];
        int pos = atomicAdd(&cursor[d], 1);
        edge_src[pos] = src[e];
    }
}

// ---------------- aggregation, epilogue writes bf16 hi/lo split ----------------
__global__ __launch_bounds__(128) void agg_kernel(const float* __restrict__ x,
        const int* __restrict__ edge_src, const int* __restrict__ row_ptr,
        const float* __restrict__ norm_out, const float* __restrict__ norm_in,
        ushort_t* __restrict__ a_hi, ushort_t* __restrict__ a_lo) {
    int d = blockIdx.x;
    int t = threadIdx.x;  // 128 threads x float4 = 512 feats
    float4 acc = make_float4(0.f, 0.f, 0.f, 0.f);
    if (d < N_NODES) {
        int beg = row_ptr[d], end = row_ptr[d + 1];
        const float4* x4 = (const float4*)x;
        for (int e = beg; e < end; e++) {
            int s = edge_src[e];
            float w = norm_out[s];
            float4 v = x4[s * (FEAT / 4) + t];
            acc.x += w * v.x;
            acc.y += w * v.y;
            acc.z += w * v.z;
            acc.w += w * v.w;
        }
        float ni = norm_in[d];
        acc.x *= ni; acc.y *= ni; acc.z *= ni; acc.w *= ni;
    }
    float vv[4] = {acc.x, acc.y, acc.z, acc.w};
    ushort_t h[4], l[4];
#pragma unroll
    for (int i = 0; i < 4; i++) {
        h[i] = f2bf(vv[i]);
        l[i] = f2bf(vv[i] - bf2f(h[i]));
    }
    ((ushort4*)a_hi)[d * (FEAT / 4) + t] = make_ushort4(h[0], h[1], h[2], h[3]);
    ((ushort4*)a_lo)[d * (FEAT / 4) + t] = make_ushort4(l[0], l[1], l[2], l[3]);
}

// ---------------- W (KxN fp32) -> W^T hi/lo (NxK bf16), tiled transpose ----------------
__global__ __launch_bounds__(256) void wsplit_kernel(const float* __restrict__ W1,
        const float* __restrict__ W2, const float* __restrict__ W3,
        ushort_t* __restrict__ wt_hi, ushort_t* __restrict__ wt_lo) {
    __shared__ float tile[32][33];
    const float* W = blockIdx.z == 0 ? W1 : (blockIdx.z == 1 ? W2 : W3);
    ushort_t* th = wt_hi + (size_t)blockIdx.z * 512 * 512;
    ushort_t* tl = wt_lo + (size_t)blockIdx.z * 512 * 512;
    int tx = threadIdx.x, ty = threadIdx.y;   // block (32,8)
    int n0 = blockIdx.x * 32, k0 = blockIdx.y * 32;
#pragma unroll
    for (int i = 0; i < 4; i++)
        tile[ty + i * 8][tx] = W[(size_t)(k0 + ty + i * 8) * 512 + n0 + tx];
    __syncthreads();
#pragma unroll
    for (int i = 0; i < 4; i++) {
        float v = tile[tx][ty + i * 8];          // = W[k0+tx][n0+ty+i*8]
        int n = n0 + ty + i * 8, k = k0 + tx;
        ushort_t hb = f2bf(v);
        th[(size_t)n * 512 + k] = hb;
        tl[(size_t)n * 512 + k] = f2bf(v - bf2f(hb));
    }
}

// ---------------- split-bf16 MFMA GEMM: C = A(M x 512) @ W(512 x 512) + bias ----------------
// A given as hi/lo bf16 (row-major, M_PAD x 512), W given as W^T hi/lo (512 x 512 bf16).
// BM=64, BN=128, BK=32; 256 threads = 4 waves, each wave 32x64 (2x4 MFMA 16x16 tiles).
template <bool RELU>
__global__ __launch_bounds__(256) void mfma_gemm(const ushort_t* __restrict__ A_hi,
        const ushort_t* __restrict__ A_lo, const ushort_t* __restrict__ Bt_hi,
        const ushort_t* __restrict__ Bt_lo, const float* __restrict__ bias,
        float* __restrict__ C) {
    __shared__ __align__(16) ushort_t lsAh[64 * 32];
    __shared__ __align__(16) ushort_t lsAl[64 * 32];
    __shared__ __align__(16) ushort_t lsBh[128 * 32];
    __shared__ __align__(16) ushort_t lsBl[128 * 32];
    int tid = threadIdx.x;
    int wave = tid >> 6, lane = tid & 63;
    int row0 = blockIdx.x * 64;
    int col0 = blockIdx.y * 128;
    int wm = wave & 1, wn = wave >> 1;
    int lr = lane & 15, lq = lane >> 4;

    // staging: each global_load_lds(16B) moves 16 rows (64B/row of the k-strip)
    int srow = lane >> 2;          // 0..15
    int sk = (lane & 3) * 8;       // ushort offset (8 ush = 16 B)
    const ushort_t* gAh = A_hi + (size_t)(row0 + wave * 16 + srow) * 512 + sk;
    const ushort_t* gAl = A_lo + (size_t)(row0 + wave * 16 + srow) * 512 + sk;
    const ushort_t* gB0h = Bt_hi + (size_t)(col0 + wave * 32 + srow) * 512 + sk;
    const ushort_t* gB0l = Bt_lo + (size_t)(col0 + wave * 32 + srow) * 512 + sk;
    const ushort_t* gB1h = Bt_hi + (size_t)(col0 + wave * 32 + 16 + srow) * 512 + sk;
    const ushort_t* gB1l = Bt_lo + (size_t)(col0 + wave * 32 + 16 + srow) * 512 + sk;
    ushort_t* lAh = &lsAh[wave * 16 * 32 + lane * 8];
    ushort_t* lAl = &lsAl[wave * 16 * 32 + lane * 8];
    ushort_t* lB0h = &lsBh[wave * 32 * 32 + lane * 8];
    ushort_t* lB0l = &lsBl[wave * 32 * 32 + lane * 8];
    ushort_t* lB1h = &lsBh[(wave * 32 + 16) * 32 + lane * 8];
    ushort_t* lB1l = &lsBl[(wave * 32 + 16) * 32 + lane * 8];

    f32x4 acc[2][4] = {};

    for (int k0 = 0; k0 < 512; k0 += 32) {
        load_lds16(gAh + k0, lAh);
        load_lds16(gAl + k0, lAl);
        load_lds16(gB0h + k0, lB0h);
        load_lds16(gB0l + k0, lB0l);
        load_lds16(gB1h + k0, lB1h);
        load_lds16(gB1l + k0, lB1l);
        __syncthreads();

        short8 ah[2], al[2], bh[4], bl[4];
#pragma unroll
        for (int i = 0; i < 2; i++) {
            int r = wm * 32 + i * 16 + lr;
            ah[i] = *(const short8*)&lsAh[r * 32 + lq * 8];
            al[i] = *(const short8*)&lsAl[r * 32 + lq * 8];
        }
#pragma unroll
        for (int j = 0; j < 4; j++) {
            int n = wn * 64 + j * 16 + lr;
            bh[j] = *(const short8*)&lsBh[n * 32 + lq * 8];
            bl[j] = *(const short8*)&lsBl[n * 32 + lq * 8];
        }
#pragma unroll
        for (int i = 0; i < 2; i++)
#pragma unroll
            for (int j = 0; j < 4; j++) {
                acc[i][j] = __builtin_amdgcn_mfma_f32_16x16x32_bf16(ah[i], bh[j], acc[i][j], 0, 0, 0);
                acc[i][j] = __builtin_amdgcn_mfma_f32_16x16x32_bf16(ah[i], bl[j], acc[i][j], 0, 0, 0);
                acc[i][j] = __builtin_amdgcn_mfma_f32_16x16x32_bf16(al[i], bh[j], acc[i][j], 0, 0, 0);
            }
        __syncthreads();
    }

#pragma unroll
    for (int i = 0; i < 2; i++)
#pragma unroll
        for (int j = 0; j < 4; j++) {
            int col = col0 + wn * 64 + j * 16 + lr;
            float bv = bias[col];
#pragma unroll
            for (int r = 0; r < 4; r++) {
                int row = row0 + wm * 32 + i * 16 + lq * 4 + r;
                if (row < N_NODES) {
                    float v = acc[i][j][r] + bv;
                    if (RELU) v = fmaxf(v, 0.f);
                    C[(size_t)row * 512 + col] = v;
                }
            }
        }
}

extern "C" void kernel_launch(void* const* d_in, const int* in_sizes, int n_in,
                              void* d_out, int out_size, void* d_ws, size_t ws_size,
                              hipStream_t stream) {
    const float* x  = (const float*)d_in[0];
    const float* W1 = (const float*)d_in[1];
    const float* b1 = (const float*)d_in[2];
    const float* W2 = (const float*)d_in[3];
    const float* b2 = (const float*)d_in[4];
    const float* W3 = (const float*)d_in[5];
    const float* b3 = (const float*)d_in[6];
    const int* src  = (const int*)d_in[7];
    const int* dst  = (const int*)d_in[8];
    float* out = (float*)d_out;

    // workspace layout
    int* wsi = (int*)d_ws;
    int* deg_out  = wsi;                       // 10000
    int* deg_in   = wsi + 10000;               // 10000
    float* norm_out = (float*)(wsi + 20000);   // 10000
    float* norm_in  = (float*)(wsi + 30000);   // 10000
    int* row_ptr  = wsi + 40000;               // 10001 (pad to 10016)
    int* cursor   = wsi + 50016;               // 10000
    int* edge_src = wsi + 60016;               // 160000  -> ends at int 220016
    ushort_t* wt_hi = (ushort_t*)(wsi + 220016);       // 3 * 512*512 = 786432 ush
    ushort_t* wt_lo = wt_hi + 786432;
    ushort_t* a_hi  = wt_lo + 786432;                  // M_PAD * 512
    ushort_t* a_lo  = a_hi + (size_t)M_PAD * 512;
    // total ~24.6 MB

    // d_out layout: [h4 | h3 | h2]. Stage h1 in the h4 slot (h4 written last).
    float* h4 = out;
    float* h1 = out;
    float* h3 = out + 5120000;
    float* h2 = out + 10240000;

    hipMemsetAsync(d_ws, 0, 20000 * sizeof(int), stream);  // deg_out + deg_in

    deg_kernel<<<(N_EDGES + 255) / 256, 256, 0, stream>>>(src, dst, deg_out, deg_in);
    norm_kernel<<<(N_NODES + 255) / 256, 256, 0, stream>>>(deg_out, deg_in, norm_out, norm_in);
    scan_kernel<<<1, 256, 0, stream>>>(deg_in, row_ptr, cursor);
    fill_kernel<<<(N_EDGES + 255) / 256, 256, 0, stream>>>(src, dst, cursor, edge_src);
    wsplit_kernel<<<dim3(16, 16, 3), dim3(32, 8), 0, stream>>>(W1, W2, W3, wt_hi, wt_lo);

    dim3 ggrid(M_PAD / 64, 4);
    ushort_t* wt1h = wt_hi;              ushort_t* wt1l = wt_lo;
    ushort_t* wt2h = wt_hi + 262144;     ushort_t* wt2l = wt_lo + 262144;
    ushort_t* wt3h = wt_hi + 524288;     ushort_t* wt3l = wt_lo + 524288;

    // layer 1
    agg_kernel<<<M_PAD, 128, 0, stream>>>(x, edge_src, row_ptr, norm_out, norm_in, a_hi, a_lo);
    mfma_gemm<true><<<ggrid, 256, 0, stream>>>(a_hi, a_lo, wt1h, wt1l, b1, h1);
    // layer 2
    agg_kernel<<<M_PAD, 128, 0, stream>>>(h1, edge_src, row_ptr, norm_out, norm_in, a_hi, a_lo);
    mfma_gemm<true><<<ggrid, 256, 0, stream>>>(a_hi, a_lo, wt2h, wt2l, b2, h2);
    // layers 3 & 4 share the aggregation of h2
    agg_kernel<<<M_PAD, 128, 0, stream>>>(h2, edge_src, row_ptr, norm_out, norm_in, a_hi, a_lo);
    mfma_gemm<true><<<ggrid, 256, 0, stream>>>(a_hi, a_lo, wt2h, wt2l, b2, h3);
    mfma_gemm<false><<<ggrid, 256, 0, stream>>>(a_hi, a_lo, wt3h, wt3l, b3, h4);
}